// Round 5
// baseline (281.293 us; speedup 1.0000x reference)
//
#include <hip/hip_runtime.h>
#include <hip/hip_bf16.h>
#include <math.h>

// Problem constants (B=4, T=1024, C=768, E=8, K=2)
#define N_TOK 4096
#define CDIM  768
#define E_EXP 8
#define CAPC  2048
#define HDIM  3072   // 4*C

typedef __attribute__((ext_vector_type(8))) short short8;
typedef __attribute__((ext_vector_type(4))) float floatx4;

#define VMCNT(n) asm volatile("s_waitcnt vmcnt(" #n ")" ::: "memory")
#define LGKM(n)  asm volatile("s_waitcnt lgkmcnt(" #n ")" ::: "memory")
#define SB0()    __builtin_amdgcn_sched_barrier(0)

static __device__ __forceinline__ unsigned short f2bf(float f) {
  __hip_bfloat16 h = __float2bfloat16(f);
  return __builtin_bit_cast(unsigned short, h);
}

// ---------------------------------------------------------------------------
// K1: transpose + f32->bf16 convert.  in: [E][R][Cc] f32 -> out: [E][Cc][R] bf16
// ---------------------------------------------------------------------------
__global__ __launch_bounds__(256)
void transpose_convert(const float* __restrict__ in, __hip_bfloat16* __restrict__ out,
                       int R, int Cc)
{
  __shared__ float tile[32][33];
  const int e  = blockIdx.z;
  const int c0 = blockIdx.x * 32;
  const int r0 = blockIdx.y * 32;
  const float* ie = in + (size_t)e * R * Cc;
  __hip_bfloat16* oe = out + (size_t)e * Cc * R;
  const int t = threadIdx.x;
  {
    const int r = t >> 3, c = (t & 7) * 4;
    const float4 v = *(const float4*)(ie + (size_t)(r0 + r) * Cc + c0 + c);
    tile[r][c + 0] = v.x; tile[r][c + 1] = v.y; tile[r][c + 2] = v.z; tile[r][c + 3] = v.w;
  }
  __syncthreads();
  {
    const int cc = t >> 3, rr = (t & 7) * 4;
    ushort4 o;
    o.x = f2bf(tile[rr + 0][cc]);
    o.y = f2bf(tile[rr + 1][cc]);
    o.z = f2bf(tile[rr + 2][cc]);
    o.w = f2bf(tile[rr + 3][cc]);
    *(ushort4*)((unsigned short*)oe + (size_t)(c0 + cc) * R + r0 + rr) = o;
  }
}

// ---------------------------------------------------------------------------
// K2: router — logits = x @ w_g^T, top-2 + softmax over the two kept logits.
// ---------------------------------------------------------------------------
__global__ __launch_bounds__(256)
void router_kernel(const float* __restrict__ x, const float* __restrict__ wg,
                   int* __restrict__ eidx, float* __restrict__ pval)
{
  const int wv = threadIdx.x >> 6, lane = threadIdx.x & 63;
  const int n = blockIdx.x * 4 + wv;
  const float* xr = x + (size_t)n * CDIM;
  float acc[E_EXP] = {0.f, 0.f, 0.f, 0.f, 0.f, 0.f, 0.f, 0.f};
#pragma unroll
  for (int i = 0; i < CDIM / 64; ++i) {
    const float xv = xr[i * 64 + lane];
#pragma unroll
    for (int e = 0; e < E_EXP; ++e)
      acc[e] = fmaf(xv, wg[e * CDIM + i * 64 + lane], acc[e]);
  }
#pragma unroll
  for (int e = 0; e < E_EXP; ++e) {
#pragma unroll
    for (int off = 32; off > 0; off >>= 1)
      acc[e] += __shfl_xor(acc[e], off);
  }
  if (lane == 0) {
    int e0 = 0; float v0 = acc[0];
#pragma unroll
    for (int e = 1; e < E_EXP; ++e) if (acc[e] > v0) { v0 = acc[e]; e0 = e; }
    int e1 = -1; float v1 = -3.4e38f;
#pragma unroll
    for (int e = 0; e < E_EXP; ++e) if (e != e0 && acc[e] > v1) { v1 = acc[e]; e1 = e; }
    const float ex = __expf(v1 - v0);
    const float inv = 1.f / (1.f + ex);
    eidx[n] = e0; eidx[N_TOK + n] = e1;
    pval[n] = inv; pval[N_TOK + n] = ex * inv;
  }
}

// ---------------------------------------------------------------------------
// K3: init slot_token to -1
// ---------------------------------------------------------------------------
__global__ void init_slots(int* __restrict__ p)
{
  p[blockIdx.x * 256 + threadIdx.x] = -1;
}

// ---------------------------------------------------------------------------
// K4: capacity scan (k-major reference order), single block Hillis-Steele.
// ---------------------------------------------------------------------------
__global__ __launch_bounds__(256)
void scan_kernel(const int* __restrict__ eidx, int* __restrict__ slot,
                 int* __restrict__ slot_token)
{
  const int t = threadIdx.x;
  const int base = t * 32;
  int e_local[32];
  int cnt[E_EXP] = {0, 0, 0, 0, 0, 0, 0, 0};
#pragma unroll
  for (int i = 0; i < 32; ++i) {
    const int e = eidx[base + i];
    e_local[i] = e;
    cnt[e]++;
  }
  __shared__ int hist[256][E_EXP];
#pragma unroll
  for (int e = 0; e < E_EXP; ++e) hist[t][e] = cnt[e];
  __syncthreads();
  for (int off = 1; off < 256; off <<= 1) {
    int v[E_EXP] = {0, 0, 0, 0, 0, 0, 0, 0};
    if (t >= off) {
#pragma unroll
      for (int e = 0; e < E_EXP; ++e) v[e] = hist[t - off][e];
    }
    __syncthreads();
    if (t >= off) {
#pragma unroll
      for (int e = 0; e < E_EXP; ++e) hist[t][e] += v[e];
    }
    __syncthreads();
  }
  int run[E_EXP];
#pragma unroll
  for (int e = 0; e < E_EXP; ++e) run[e] = hist[t][e] - cnt[e];
#pragma unroll
  for (int i = 0; i < 32; ++i) {
    const int a = base + i;
    const int e = e_local[i];
    const int r = run[e]++;
    const int s = (r < CAPC) ? r : -1;
    slot[a] = s;
    if (s >= 0) slot_token[e * CAPC + s] = (a < N_TOK) ? a : (a - N_TOK);
  }
}

// ---------------------------------------------------------------------------
// K5: dispatch — exp_in row = bf16(x[token]) or zeros.  One wave/slot.
// ---------------------------------------------------------------------------
__global__ __launch_bounds__(256)
void dispatch_kernel(const float* __restrict__ x, const int* __restrict__ slot_token,
                     __hip_bfloat16* __restrict__ xin)
{
  const int wv = threadIdx.x >> 6, lane = threadIdx.x & 63;
  const int s = blockIdx.x * 4 + wv;
  const int n = slot_token[s];
  unsigned short* orow = (unsigned short*)xin + (size_t)s * CDIM;
  if (n >= 0) {
    const float4* xr = (const float4*)(x + (size_t)n * CDIM);
#pragma unroll
    for (int i = 0; i < 3; ++i) {
      const float4 v = xr[i * 64 + lane];
      ushort4 o;
      o.x = f2bf(v.x); o.y = f2bf(v.y); o.z = f2bf(v.z); o.w = f2bf(v.w);
      *(ushort4*)(orow + (size_t)(i * 64 + lane) * 4) = o;
    }
  } else {
    const ushort4 z = {0, 0, 0, 0};
#pragma unroll
    for (int i = 0; i < 3; ++i)
      *(ushort4*)(orow + (size_t)(i * 64 + lane) * 4) = z;
  }
}

// ---------------------------------------------------------------------------
// K6: 128x128-tile batched GEMM, BK=64, 4 waves (2Mx2N, 64x64/wave),
// dbuf 64 KiB LDS -> 2 blocks/CU (cross-block pipe overlap), counted vmcnt.
//
// LDS per buffer (kt&1): A[128 rows][128B] @ 0, B[128 rows][128B] @ 16K.
// XOR swizzle kb ^= (row&7)<<4 on both stage-source and read (proven r1-r4).
// Per K-tile:
//   VMCNT(8); barrier          // buf[kt] resident (stage kt+2 outstanding = 8)
//   reads kk0 (8 b128), kk1 (8)
//   LGKM(8) -> MFMA kk0 (16);  LGKM(0) -> MFMA kk1 (16)
//   barrier                    // all waves done reading buf[kt]
//   stage A,B(kt+2) -> buf[kt&1]   (8 gload_lds)
// FIFO ledger (gload units): prologue A0,B0,A1,B1 = 16 outstanding;
//   entry vmcnt(8) completes exactly tile kt; tails <8,nostage>, <0,nostage>.
// ---------------------------------------------------------------------------
__device__ __forceinline__ void stage_ab(const __hip_bfloat16* Ae, const __hip_bfloat16* Be,
                                         char* lds, int K, int kt, int isB,
                                         int wv, int lane)
{
  const char* src = (const char*)(isB ? Be : Ae);
  char* dst = lds + (kt & 1) * 32768 + isB * 16384;
#pragma unroll
  for (int j = 0; j < 4; ++j) {
    const int li = j * 32 + wv * 8 + (lane >> 3);
    const int kb = ((lane & 7) * 16) ^ ((li & 7) << 4);  // pre-swizzled source
    const char* g = src + ((size_t)li * K + (size_t)kt * 64) * 2 + kb;
    char* lp = dst + j * 4096 + wv * 1024;  // + lane*16 implicit (HW scatter)
    __builtin_amdgcn_global_load_lds((const __attribute__((address_space(1))) unsigned int*)g,
                                     (__attribute__((address_space(3))) unsigned int*)lp, 16, 0, 0);
  }
}

template<int VME, bool S2>
__device__ __forceinline__ void ktile(int kt, char* lds,
                                      const __hip_bfloat16* Ae, const __hip_bfloat16* Be,
                                      int K, floatx4 (&acc)[4][4],
                                      int wm, int wn, int fr, int fk, int wv, int lane)
{
  if constexpr (VME == 8) VMCNT(8); else VMCNT(0);
  __builtin_amdgcn_s_barrier();
  SB0();
  const char* bufA = lds + ((kt & 1) ? 32768 : 0);
  const char* bufB = bufA + 16384;
  short8 a[4][2], b[4][2];

  // reads: kk0 first (8 x b128), then kk1 (8 x b128)
#pragma unroll
  for (int mi = 0; mi < 4; ++mi) {
    const int lr = wm * 64 + mi * 16 + fr;
    a[mi][0] = *(const short8*)(bufA + lr * 128 + ((fk * 16) ^ ((lr & 7) << 4)));
  }
#pragma unroll
  for (int ni = 0; ni < 4; ++ni) {
    const int lj = wn * 64 + ni * 16 + fr;
    b[ni][0] = *(const short8*)(bufB + lj * 128 + ((fk * 16) ^ ((lj & 7) << 4)));
  }
  SB0();
#pragma unroll
  for (int mi = 0; mi < 4; ++mi) {
    const int lr = wm * 64 + mi * 16 + fr;
    a[mi][1] = *(const short8*)(bufA + lr * 128 + ((64 + fk * 16) ^ ((lr & 7) << 4)));
  }
#pragma unroll
  for (int ni = 0; ni < 4; ++ni) {
    const int lj = wn * 64 + ni * 16 + fr;
    b[ni][1] = *(const short8*)(bufB + lj * 128 + ((64 + fk * 16) ^ ((lj & 7) << 4)));
  }
  SB0();
  LGKM(8); SB0();                      // kk0 fragments resident
  __builtin_amdgcn_s_setprio(1);
#pragma unroll
  for (int mi = 0; mi < 4; ++mi)
#pragma unroll
    for (int ni = 0; ni < 4; ++ni)
      acc[mi][ni] = __builtin_amdgcn_mfma_f32_16x16x32_bf16(a[mi][0], b[ni][0], acc[mi][ni], 0, 0, 0);
  __builtin_amdgcn_s_setprio(0);
  SB0();
  LGKM(0); SB0();                      // kk1 resident; this wave done with buf[kt]
  __builtin_amdgcn_s_setprio(1);
#pragma unroll
  for (int mi = 0; mi < 4; ++mi)
#pragma unroll
    for (int ni = 0; ni < 4; ++ni)
      acc[mi][ni] = __builtin_amdgcn_mfma_f32_16x16x32_bf16(a[mi][1], b[ni][1], acc[mi][ni], 0, 0, 0);
  __builtin_amdgcn_s_setprio(0);
  SB0();
  __builtin_amdgcn_s_barrier();        // all waves done reading buf[kt]
  if (S2) {
    stage_ab(Ae, Be, lds, K, kt + 2, 0, wv, lane);
    stage_ab(Ae, Be, lds, K, kt + 2, 1, wv, lane);
  }
  SB0();
}

template<int GELU_OUT>
__global__ __launch_bounds__(256, 2)
void gemm2b(const __hip_bfloat16* __restrict__ A, const __hip_bfloat16* __restrict__ Bt,
            const float* __restrict__ bias, void* __restrict__ Cout,
            int M, int Nn, int K, int nbx, int nby)
{
  extern __shared__ __align__(16) char lds[];
  const int nwg = gridDim.x;
  int wg = blockIdx.x;
  wg = (wg & 7) * (nwg >> 3) + (wg >> 3);       // bijective XCD chunking (nwg%8==0)
  const int e = wg / (nbx * nby);
  const int rem = wg % (nbx * nby);
  const int by = rem / nbx, bx = rem % nbx;
  const int t = threadIdx.x, wv = t >> 6, lane = t & 63;
  const int wm = wv >> 1, wn = wv & 1;          // 2x2 wave grid, 64x64 per wave
  const int fr = lane & 15, fk = lane >> 4;
  const int ntk = K >> 6;

  const __hip_bfloat16* Ae = A + (size_t)e * M * K + (size_t)by * 128 * K;
  const __hip_bfloat16* Be = Bt + (size_t)e * Nn * K + (size_t)bx * 128 * K;

  floatx4 acc[4][4] = {};

  // prologue FIFO: A0,B0 (buf0), A1,B1 (buf1)  = 16 gloads outstanding
  stage_ab(Ae, Be, lds, K, 0, 0, wv, lane);
  stage_ab(Ae, Be, lds, K, 0, 1, wv, lane);
  stage_ab(Ae, Be, lds, K, 1, 0, wv, lane);
  stage_ab(Ae, Be, lds, K, 1, 1, wv, lane);
  SB0();

  for (int kt = 0; kt < ntk - 2; ++kt)
    ktile<8, true>(kt, lds, Ae, Be, K, acc, wm, wn, fr, fk, wv, lane);
  ktile<8, false>(ntk - 2, lds, Ae, Be, K, acc, wm, wn, fr, fk, wv, lane);
  ktile<0, false>(ntk - 1, lds, Ae, Be, K, acc, wm, wn, fr, fk, wv, lane);

  // epilogue: C/D layout col = lane&15, row = (lane>>4)*4 + j
  const float* be = bias + (size_t)e * Nn;
  const size_t cbase = (size_t)e * M * Nn;
  const int m0 = by * 128, n0 = bx * 128;

  if (GELU_OUT) {
    // LDS-staged coalesced bf16 store; wave-private 2KB region.
    __builtin_amdgcn_s_barrier();
    unsigned short* ep = (unsigned short*)(lds + wv * 2048);
    unsigned short* Cb = (unsigned short*)Cout + cbase;
    float bcol[4];
#pragma unroll
    for (int ni = 0; ni < 4; ++ni) bcol[ni] = be[n0 + wn * 64 + ni * 16 + fr];
#pragma unroll
    for (int mi = 0; mi < 4; ++mi) {
#pragma unroll
      for (int ni = 0; ni < 4; ++ni)
#pragma unroll
        for (int j = 0; j < 4; ++j) {
          float v = acc[mi][ni][j] + bcol[ni];
          v = 0.5f * v * (1.0f + erff(v * 0.70710678118654752f));
          const int row = fk * 4 + j;
          *(unsigned short*)((char*)ep + row * 128 + ((ni * 32 + fr * 2) ^ (fk << 5))) = f2bf(v);
        }
      LGKM(0); SB0();
      const int r = lane & 15;
      const int grow = m0 + wm * 64 + mi * 16 + r;
#pragma unroll
      for (int it = 0; it < 2; ++it) {
        const int q = (lane >> 4) + it * 4;
        const short8 vv = *(const short8*)((char*)ep + r * 128 + ((q * 16) ^ ((r >> 2) << 5)));
        *(short8*)(Cb + (size_t)grow * Nn + n0 + wn * 64 + q * 8) = vv;
      }
      LGKM(0); SB0();
    }
  } else {
#pragma unroll
    for (int ni = 0; ni < 4; ++ni) {
      const int col = n0 + wn * 64 + ni * 16 + fr;
      const float b = be[col];
#pragma unroll
      for (int mi = 0; mi < 4; ++mi) {
        const int rbase = m0 + wm * 64 + mi * 16 + fk * 4;
#pragma unroll
        for (int j = 0; j < 4; ++j) {
          ((float*)Cout)[cbase + (size_t)(rbase + j) * Nn + col] = acc[mi][ni][j] + b;
        }
      }
    }
  }
}

// ---------------------------------------------------------------------------
// K7: combine — out[n] = w0*exp_out[e0][s0] + w1*exp_out[e1][s1]
// ---------------------------------------------------------------------------
__global__ __launch_bounds__(256)
void combine_kernel(const float* __restrict__ eout, const int* __restrict__ eidx,
                    const float* __restrict__ pval, const int* __restrict__ slot,
                    float* __restrict__ out)
{
  const int wv = threadIdx.x >> 6, lane = threadIdx.x & 63;
  const int n = blockIdx.x * 4 + wv;
  const int e0 = eidx[n], e1 = eidx[N_TOK + n];
  int s0 = slot[n], s1 = slot[N_TOK + n];
  const float w0 = (s0 >= 0) ? pval[n] : 0.f;
  const float w1 = (s1 >= 0) ? pval[N_TOK + n] : 0.f;
  s0 = (s0 >= 0) ? s0 : 0;
  s1 = (s1 >= 0) ? s1 : 0;
  const float4* r0 = (const float4*)(eout + ((size_t)e0 * CAPC + s0) * CDIM);
  const float4* r1 = (const float4*)(eout + ((size_t)e1 * CAPC + s1) * CDIM);
  float4* o = (float4*)(out + (size_t)n * CDIM);
#pragma unroll
  for (int i = 0; i < 3; ++i) {
    const float4 a = r0[i * 64 + lane];
    const float4 b = r1[i * 64 + lane];
    float4 c;
    c.x = w0 * a.x + w1 * b.x;
    c.y = w0 * a.y + w1 * b.y;
    c.z = w0 * a.z + w1 * b.z;
    c.w = w0 * a.w + w1 * b.w;
    o[i * 64 + lane] = c;
  }
}

// ---------------------------------------------------------------------------
extern "C" void kernel_launch(void* const* d_in, const int* in_sizes, int n_in,
                              void* d_out, int out_size, void* d_ws, size_t ws_size,
                              hipStream_t stream)
{
  const float* x   = (const float*)d_in[0];
  const float* wg  = (const float*)d_in[1];
  const float* cfc = (const float*)d_in[2];
  const float* fcb = (const float*)d_in[3];
  const float* cpr = (const float*)d_in[4];
  const float* prb = (const float*)d_in[5];
  float* out = (float*)d_out;

  char* ws = (char*)d_ws;
  size_t off = 0;
  auto take = [&](size_t bytes) -> void* {
    void* p = ws + off;
    off += (bytes + 255) & ~(size_t)255;
    return p;
  };
  __hip_bfloat16* wfcT = (__hip_bfloat16*)take((size_t)E_EXP * HDIM * CDIM * 2); // [E][3072][768]
  __hip_bfloat16* wprT = (__hip_bfloat16*)take((size_t)E_EXP * CDIM * HDIM * 2); // [E][768][3072]
  __hip_bfloat16* xin  = (__hip_bfloat16*)take((size_t)E_EXP * CAPC * CDIM * 2); // [E][CAP][768]
  __hip_bfloat16* hbuf = (__hip_bfloat16*)take((size_t)E_EXP * CAPC * HDIM * 2); // [E][CAP][3072]
  float*          eout = (float*)take((size_t)E_EXP * CAPC * CDIM * 4);          // [E][CAP][768]
  int*   eidx = (int*)take((size_t)2 * N_TOK * 4);
  float* pv   = (float*)take((size_t)2 * N_TOK * 4);
  int*   slot = (int*)take((size_t)2 * N_TOK * 4);
  int*   stok = (int*)take((size_t)E_EXP * CAPC * 4);

  hipFuncSetAttribute((const void*)gemm2b<1>, hipFuncAttributeMaxDynamicSharedMemorySize, 65536);
  hipFuncSetAttribute((const void*)gemm2b<0>, hipFuncAttributeMaxDynamicSharedMemorySize, 65536);

  // weight transpose+convert
  transpose_convert<<<dim3(HDIM / 32, CDIM / 32, E_EXP), 256, 0, stream>>>(cfc, wfcT, CDIM, HDIM);
  transpose_convert<<<dim3(CDIM / 32, HDIM / 32, E_EXP), 256, 0, stream>>>(cpr, wprT, HDIM, CDIM);

  router_kernel<<<N_TOK / 4, 256, 0, stream>>>(x, wg, eidx, pv);
  init_slots<<<(E_EXP * CAPC) / 256, 256, 0, stream>>>(stok);
  scan_kernel<<<1, 256, 0, stream>>>(eidx, slot, stok);
  dispatch_kernel<<<(E_EXP * CAPC) / 4, 256, 0, stream>>>(x, stok, xin);

  // GEMM1 + bias + exact GELU -> h (bf16): per-expert M=2048, N=3072, K=768
  gemm2b<1><<<3072, 256, 65536, stream>>>(xin, wfcT, fcb, hbuf, CAPC, HDIM, CDIM, 24, 16);
  // GEMM2 + bias -> exp_out (f32): per-expert M=2048, N=768, K=3072
  gemm2b<0><<<768, 256, 65536, stream>>>(hbuf, wprT, prb, eout, CAPC, CDIM, HDIM, 6, 16);

  combine_kernel<<<N_TOK / 4, 256, 0, stream>>>(eout, eidx, pv, slot, out);
}